// Round 11
// baseline (305.008 us; speedup 1.0000x reference)
//
#include <hip/hip_runtime.h>
#include <hip/hip_bf16.h>

constexpr int NN = 40000;
constexpr int NE = 640000;
constexpr int D  = 128;
constexpr int NG = 128;

__device__ __forceinline__ ushort f2bf(float x) {
  union { float f; unsigned u; } c{x};
  const unsigned r = (c.u + 0x7FFFu + ((c.u >> 16) & 1u)) >> 16;  // RNE
  return (ushort)r;
}
__device__ __forceinline__ float bf2f(ushort b) {
  return __uint_as_float(((unsigned)b) << 16);
}

using short8 = __attribute__((ext_vector_type(8))) short;
using f32x4  = __attribute__((ext_vector_type(4))) float;

// ---------------------------------------------------------------------------
// Fused: histogram + f32->bf16 conversion of feat/W + hg zeroing.
// ---------------------------------------------------------------------------
constexpr int FEAT4  = NN * D / 4;            // 1,280,000 float4s
constexpr int W4     = D * D / 4;             // 4,096 float4s per W
constexpr int HIST_B = (NE + 255) / 256;      // 2,500
constexpr int CVT_B  = (FEAT4 + 3 * W4 + 255) / 256;  // 5,049
constexpr int HG4    = NG * 3 * D / 4;        // 12,288 float4s
constexpr int HGZ_B  = (HG4 + 255) / 256;     // 48

__global__ __launch_bounds__(256)
void hist_cvt(const int* __restrict__ col, int* __restrict__ cnt,
              const float* __restrict__ feat, const float* __restrict__ w0,
              const float* __restrict__ w1, const float* __restrict__ w2,
              ushort* __restrict__ featb, ushort* __restrict__ Wb,
              float* __restrict__ hg) {
  const int b = blockIdx.x;
  if (b < HIST_B) {
    const int e = b * 256 + threadIdx.x;
    if (e < NE) atomicAdd(&cnt[col[e]], 1);
    return;
  }
  if (b >= HIST_B + CVT_B) {
    const int i = (b - HIST_B - CVT_B) * 256 + threadIdx.x;
    if (i < HG4) ((float4*)hg)[i] = make_float4(0.f, 0.f, 0.f, 0.f);
    return;
  }
  const int i = (b - HIST_B) * 256 + threadIdx.x;
  const float* src; ushort* dst; int idx;
  if (i < FEAT4) { src = feat; dst = featb; idx = i; }
  else if (i < FEAT4 + 3 * W4) {
    const int j = i - FEAT4;
    const int ws = j >> 12;
    idx = j & (W4 - 1);
    src = ws == 0 ? w0 : (ws == 1 ? w1 : w2);
    dst = Wb + (size_t)ws * D * D;
  } else return;
  const float4 v = ((const float4*)src)[idx];
  ushort4 p;
  p.x = f2bf(v.x); p.y = f2bf(v.y); p.z = f2bf(v.z); p.w = f2bf(v.w);
  ((ushort4*)dst)[idx] = p;
}

// ---------------------------------------------------------------------------
// Single-pass decoupled-lookback exclusive scan of cnt[NN] -> off, cur.
// ---------------------------------------------------------------------------
constexpr int SCAN_B  = 1024;
constexpr int SCAN_NB = (NN + SCAN_B - 1) / SCAN_B;  // 40

__global__ __launch_bounds__(SCAN_B)
void scan_onepass(const int* __restrict__ cnt, int* __restrict__ off,
                  int* __restrict__ cur, int* __restrict__ bstate,
                  int* __restrict__ ticket) {
  __shared__ int bid_s;
  if (threadIdx.x == 0) bid_s = atomicAdd(ticket, 1);
  __syncthreads();
  const int b   = bid_s;
  const int tid = threadIdx.x;
  const int i   = b * SCAN_B + tid;
  const int v   = (i < NN) ? cnt[i] : 0;

  __shared__ int buf[SCAN_B];
  buf[tid] = v;
  __syncthreads();
  for (int s = 1; s < SCAN_B; s <<= 1) {
    const int t = (tid >= s) ? buf[tid - s] : 0;
    __syncthreads();
    buf[tid] += t;
    __syncthreads();
  }
  const int total = buf[SCAN_B - 1];

  __shared__ int exc_s;
  if (tid == 0) {
    if (b == 0) {
      __hip_atomic_store(&bstate[0], (2 << 24) | total, __ATOMIC_RELEASE,
                         __HIP_MEMORY_SCOPE_AGENT);
      exc_s = 0;
    } else {
      __hip_atomic_store(&bstate[b], (1 << 24) | total, __ATOMIC_RELEASE,
                         __HIP_MEMORY_SCOPE_AGENT);
      int exc = 0, p = b - 1;
      while (true) {
        const int st = __hip_atomic_load(&bstate[p], __ATOMIC_ACQUIRE,
                                         __HIP_MEMORY_SCOPE_AGENT);
        const int fl = st >> 24;
        if (fl == 2) { exc += st & 0xFFFFFF; break; }
        if (fl == 1) { exc += st & 0xFFFFFF; --p; }
      }
      __hip_atomic_store(&bstate[b], (2 << 24) | (exc + total),
                         __ATOMIC_RELEASE, __HIP_MEMORY_SCOPE_AGENT);
      exc_s = exc;
    }
  }
  __syncthreads();
  const int e = exc_s + buf[tid] - v;   // global exclusive prefix
  if (i < NN) { off[i] = e; cur[i] = e; }
  if (b == SCAN_NB - 1 && tid == SCAN_B - 1) off[NN] = exc_s + total;  // = NE
}

// ---------------------------------------------------------------------------
// GEMM body (MFMA 16x16x32 bf16), shared by fill_gemm0 and gemm_pool.
// ---------------------------------------------------------------------------
constexpr int GEMM_B = NN / 64;  // 625

__device__ __forceinline__ void gemm_body(int b, int tid,
                                          const ushort* __restrict__ A,
                                          const ushort* __restrict__ Wb,
                                          ushort* __restrict__ out) {
  const int wave = tid >> 6, lane = tid & 63;
  const int n0 = b * 64 + wave * 16;
  const int r  = lane & 15, kg = lane >> 4;

  short8 afr[4];
  const ushort* arow = A + (size_t)(n0 + r) * D + kg * 8;
#pragma unroll
  for (int kt = 0; kt < 4; ++kt)
    afr[kt] = *(const short8*)(arow + kt * 32);

#pragma unroll
  for (int ct = 0; ct < 8; ++ct) {
    f32x4 acc = {0.f, 0.f, 0.f, 0.f};
    const ushort* wrow = Wb + (size_t)(ct * 16 + r) * D + kg * 8;
#pragma unroll
    for (int kt = 0; kt < 4; ++kt) {
      const short8 bfr = *(const short8*)(wrow + kt * 32);
      acc = __builtin_amdgcn_mfma_f32_16x16x32_bf16(afr[kt], bfr, acc, 0, 0, 0);
    }
#pragma unroll
    for (int q = 0; q < 4; ++q) {
      const int m = kg * 4 + q;
      out[(size_t)(n0 + m) * D + ct * 16 + r] = f2bf(acc[q]);
    }
  }
}

// ---------------------------------------------------------------------------
// Fused: fill (CSR scatter, 4B packed edges) + gemm layer 0.
// fill blocks are latency-bound scatter; gemm blocks keep the MFMA pipe busy.
// ---------------------------------------------------------------------------
__global__ __launch_bounds__(256)
void fill_gemm0(const int* __restrict__ row, const int* __restrict__ col,
                const float* __restrict__ w, int* __restrict__ cur,
                unsigned* __restrict__ epk, const ushort* __restrict__ A,
                const ushort* __restrict__ Wb, ushort* __restrict__ out) {
  const int b = blockIdx.x;
  if (b < HIST_B) {
    const int e = b * 256 + threadIdx.x;
    if (e < NE) {
      const int p = atomicAdd(&cur[col[e]], 1);
      epk[p] = ((unsigned)f2bf(w[e]) << 16) | (unsigned)row[e];
    }
    return;
  }
  gemm_body(b - HIST_B, threadIdx.x, A, Wb, out);
}

// ---------------------------------------------------------------------------
// Pooling (bf16 h source) — piggy-backed on gemm dispatches.
// ---------------------------------------------------------------------------
__device__ __forceinline__ int lbound(const int* a, int n, int key) {
  int lo = 0, hi = n;
  while (lo < hi) { const int m = (lo + hi) >> 1; if (a[m] < key) lo = m + 1; else hi = m; }
  return lo;
}

__device__ __forceinline__ void pool_body_bf16(int pb, int tid,
                                               const ushort* __restrict__ h,
                                               const int* __restrict__ batch,
                                               float* __restrict__ hg, int layer) {
  const int g    = pb >> 3;
  const int part = ((pb & 7) << 1) | (tid >> 7);  // 0..15
  const int col  = tid & 127;
  const int lo = lbound(batch, NN, g);
  const int hi = lbound(batch, NN, g + 1);
  float acc = 0.f;
  for (int n = lo + part; n < hi; n += 16)
    acc += bf2f(h[(size_t)n * D + col]);
  atomicAdd(&hg[(size_t)g * (3 * D) + layer * D + col], acc);
}

__global__ __launch_bounds__(256)
void gemm_pool(const ushort* __restrict__ A, const ushort* __restrict__ Wb,
               ushort* __restrict__ out, const ushort* __restrict__ hprev,
               const int* __restrict__ batch, float* __restrict__ hg,
               int layer) {
  const int b = blockIdx.x;
  if (b >= GEMM_B) {
    pool_body_bf16(b - GEMM_B, threadIdx.x, hprev, batch, hg, layer);
    return;
  }
  gemm_body(b, threadIdx.x, A, Wb, out);
}

// final-layer pool reads the f32 output rows
__global__ __launch_bounds__(256)
void pool_f32(const float* __restrict__ h, const int* __restrict__ batch,
              float* __restrict__ hg, int layer) {
  const int pb   = blockIdx.x;
  const int tid  = threadIdx.x;
  const int g    = pb >> 3;
  const int part = ((pb & 7) << 1) | (tid >> 7);
  const int col  = tid & 127;
  const int lo = lbound(batch, NN, g);
  const int hi = lbound(batch, NN, g + 1);
  float acc = 0.f;
  for (int n = lo + part; n < hi; n += 16)
    acc += h[(size_t)n * D + col];
  atomicAdd(&hg[(size_t)g * (3 * D) + layer * D + col], acc);
}

// ---------------------------------------------------------------------------
// Gather (CSR, bf16 rows) + PReLU — SPLIT-WAVE: 2 waves per node, each takes
// half the edge list (deg~16 -> ~8 edges/wave = one 8-wide independent load
// batch), partials combined via LDS. Halves the per-wave serial latency
// chain and doubles wave parallelism. Layers 0,1 write bf16 hb; layer 2
// writes f32 hout only (pool2 reads f32).
// NO fused hg atomics (round-7: +70µs/layer serialization).
// ---------------------------------------------------------------------------
__global__ __launch_bounds__(256)
void gather_prelu(const ushort* __restrict__ tmp, const int* __restrict__ off,
                  const unsigned* __restrict__ epk, const float* __restrict__ aP,
                  ushort* __restrict__ hb, float* __restrict__ hout) {
  __shared__ float2 part[4][64];
  const int tid  = threadIdx.x;
  const int wave = tid >> 6, lane = tid & 63;
  const int node = blockIdx.x * 2 + (wave >> 1);
  const int sub  = wave & 1;
  const int lo = off[node], hi = off[node + 1];
  const int deg = hi - lo;
  const int halfA = (deg + 1) >> 1;
  const int mylo  = lo + (sub ? halfA : 0);
  const int mycnt = sub ? (deg - halfA) : halfA;
  float ax = 0.f, ay = 0.f;

  for (int base = 0; base < mycnt; base += 64) {
    const int rem = mycnt - base;
    unsigned meta = 0u;
    if (lane < rem) meta = epk[mylo + base + lane];
    const int cnt = rem < 64 ? rem : 64;
    for (int j0 = 0; j0 < cnt; j0 += 8) {
      unsigned v[8]; float w[8];
#pragma unroll
      for (int j = 0; j < 8; ++j) {
        const unsigned m = (unsigned)__builtin_amdgcn_readlane((int)meta, j0 + j);
        w[j] = __uint_as_float(m & 0xFFFF0000u);
        v[j] = *(const unsigned*)(tmp + (size_t)(m & 0xFFFFu) * D + lane * 2);
      }
#pragma unroll
      for (int j = 0; j < 8; ++j) {
        ax += __uint_as_float(v[j] << 16) * w[j];
        ay += __uint_as_float(v[j] & 0xFFFF0000u) * w[j];
      }
    }
  }
  part[wave][lane] = make_float2(ax, ay);
  __syncthreads();
  if (sub == 0) {
    const float2 o = part[wave ^ 1][lane];
    ax += o.x; ay += o.y;
    const float alpha = aP[0];
    ax = ax >= 0.f ? ax : alpha * ax;
    ay = ay >= 0.f ? ay : alpha * ay;
    if (hout) {
      *(float2*)(hout + (size_t)node * D + lane * 2) = make_float2(ax, ay);
    } else {
      union { unsigned u; ushort s[2]; } pk;
      pk.s[0] = f2bf(ax); pk.s[1] = f2bf(ay);
      *(unsigned*)(hb + (size_t)node * D + lane * 2) = pk.u;
    }
  }
}

// ---------------------------------------------------------------------------
extern "C" void kernel_launch(void* const* d_in, const int* in_sizes, int n_in,
                              void* d_out, int out_size, void* d_ws, size_t ws_size,
                              hipStream_t stream) {
  const float* feat    = (const float*)d_in[0];
  const float* eweight = (const float*)d_in[1];
  const float* W[3]    = {(const float*)d_in[2], (const float*)d_in[3], (const float*)d_in[4]};
  const float* a[3]    = {(const float*)d_in[5], (const float*)d_in[6], (const float*)d_in[7]};
  const int*   eidx    = (const int*)d_in[8];
  const int*   batch   = (const int*)d_in[9];
  const int*   erow = eidx;
  const int*   ecol = eidx + NE;

  char* ws = (char*)d_ws;
  ushort*   tmp    = (ushort*)(ws);               // 10,240,000 B (bf16 NN x D)
  ushort*   hb     = (ushort*)(ws + 10240000);    // 10,240,000 B (bf16 h)
  ushort*   featb  = (ushort*)(ws + 20480000);    // 10,240,000 B (bf16 feat)
  int*      cnt    = (int*)(ws + 30720000);       //    160,000 B
  int*      bstate = (int*)(ws + 30880000);       //        160 B  (scan state)
  int*      ticket = (int*)(ws + 30880160);       //          4 B
  int*      off    = (int*)(ws + 30880192);       //    160,004 B
  int*      cur    = (int*)(ws + 31040256);       //    160,000 B
  unsigned* epk    = (unsigned*)(ws + 31200320);  //  2,560,000 B
  ushort*   Wb     = (ushort*)(ws + 33760320);    //     98,304 B  (3 x 128 x 128)

  float* hout = (float*)d_out;                 // NN x D (f32)
  float* hg   = hout + (size_t)NN * D;         // NG x 3D

  // zero cnt + bstate + ticket in one contiguous range
  hipMemsetAsync(cnt, 0, 160164, stream);

  hist_cvt<<<HIST_B + CVT_B + HGZ_B, 256, 0, stream>>>(
      ecol, cnt, feat, W[0], W[1], W[2], featb, Wb, hg);
  scan_onepass<<<SCAN_NB, SCAN_B, 0, stream>>>(cnt, off, cur, bstate, ticket);

  // fill + gemm layer 0 fused (independent work, shares the machine)
  fill_gemm0<<<HIST_B + GEMM_B, 256, 0, stream>>>(
      erow, ecol, eweight, cur, epk, featb, Wb, tmp);
  gather_prelu<<<NN / 2, 256, 0, stream>>>(tmp, off, epk, a[0], hb, nullptr);

  for (int l = 1; l < 3; ++l) {
    gemm_pool<<<GEMM_B + 1024, 256, 0, stream>>>(
        hb, Wb + (size_t)l * D * D, tmp, hb, batch, hg, l - 1);
    gather_prelu<<<NN / 2, 256, 0, stream>>>(
        tmp, off, epk, a[l], hb, (l == 2) ? hout : nullptr);
  }
  pool_f32<<<1024, 256, 0, stream>>>(hout, batch, hg, 2);
}